// Round 1
// baseline (368.024 us; speedup 1.0000x reference)
//
#include <hip/hip_runtime.h>
#include <hip/hip_bf16.h>

// Fused attention block: QKV proj -> causal MHA -> dense proj.
// SEQ=2048, BATCH=2, HIDDEN=2048, HEADS=16, HEAD_DIM=128.
// Strategy: convert fp32->bf16 once; all matmuls via mfma_f32_16x16x32_bf16
// with global_load_lds staging; flash attention with online softmax.

typedef __bf16 bf16x8 __attribute__((ext_vector_type(8)));
typedef __bf16 bf16x4 __attribute__((ext_vector_type(4)));
typedef float  f32x4  __attribute__((ext_vector_type(4)));

#define MROWS 4096   // SEQ*BATCH
#define NQKV  6144   // 3*HIDDEN

__device__ __forceinline__ void g2l16(const void* g, void* l) {
  __builtin_amdgcn_global_load_lds(
      (const __attribute__((address_space(1))) unsigned int*)g,
      (__attribute__((address_space(3))) unsigned int*)l, 16, 0, 0);
}

// ---------------- fp32 -> bf16 convert ----------------
__global__ void cvt_kernel(const float* __restrict__ in, __bf16* __restrict__ out, int n4) {
  int i = blockIdx.x * 256 + threadIdx.x;
  if (i < n4) {
    float4 v = ((const float4*)in)[i];
    bf16x4 o = { (__bf16)v.x, (__bf16)v.y, (__bf16)v.z, (__bf16)v.w };
    ((bf16x4*)out)[i] = o;
  }
}

// ---------------- GEMM: C[M][N] = A[M][K] * B[N][K]^T + bias ----------------
// m97 structure: 128x128 tile, BK=32, 4 waves (2x2), double-buffered LDS,
// global_load_lds width=16 staging. A,B both K-contiguous bf16.
template<int C_BF16>
__global__ __launch_bounds__(256, 2)
void gemm_bt(const __bf16* __restrict__ A, const __bf16* __restrict__ B,
             const float* __restrict__ bias, void* __restrict__ Cout,
             int M, int N, int K) {
  const int tid = threadIdx.x;
  const int lane = tid & 63;
  const int w  = tid >> 6;
  const int wm = w >> 1, wn = w & 1;
  const int m0 = blockIdx.y * 128, n0 = blockIdx.x * 128;
  const int fr = lane & 15, fh = (lane >> 4) * 8;

  __shared__ __bf16 As[2][128][32];
  __shared__ __bf16 Bs[2][128][32];

  f32x4 acc[4][4] = {};

  const int srow = tid >> 2;        // staging row within 64-row half
  const int scb  = (tid & 3) * 8;   // staging k-offset (8 bf16 = 16B)

  // prologue: stage kt=0 into buf 0
  {
    #pragma unroll
    for (int q = 0; q < 2; ++q) {
      int row = q * 64 + srow;
      g2l16(A + (size_t)(m0 + row) * K + scb,
            (char*)&As[0][0][0] + (q * 4 + w) * 1024);
      g2l16(B + (size_t)(n0 + row) * K + scb,
            (char*)&Bs[0][0][0] + (q * 4 + w) * 1024);
    }
  }
  asm volatile("s_waitcnt vmcnt(0)" ::: "memory");
  __syncthreads();

  const int KT = K >> 5;
  int buf = 0;
  for (int kt = 0; kt < KT; ++kt) {
    if (kt + 1 < KT) {
      const int k0 = (kt + 1) << 5;
      #pragma unroll
      for (int q = 0; q < 2; ++q) {
        int row = q * 64 + srow;
        g2l16(A + (size_t)(m0 + row) * K + k0 + scb,
              (char*)&As[buf ^ 1][0][0] + (q * 4 + w) * 1024);
        g2l16(B + (size_t)(n0 + row) * K + k0 + scb,
              (char*)&Bs[buf ^ 1][0][0] + (q * 4 + w) * 1024);
      }
    }
    bf16x8 af[4], bfr[4];
    #pragma unroll
    for (int m = 0; m < 4; ++m)
      af[m] = *(const bf16x8*)&As[buf][wm * 64 + m * 16 + fr][fh];
    #pragma unroll
    for (int n = 0; n < 4; ++n)
      bfr[n] = *(const bf16x8*)&Bs[buf][wn * 64 + n * 16 + fr][fh];
    #pragma unroll
    for (int m = 0; m < 4; ++m)
      #pragma unroll
      for (int n = 0; n < 4; ++n)
        acc[m][n] = __builtin_amdgcn_mfma_f32_16x16x32_bf16(af[m], bfr[n], acc[m][n], 0, 0, 0);
    __syncthreads();
    buf ^= 1;
  }

  // epilogue: C/D layout col=lane&15, row=(lane>>4)*4+reg  (m89/m91-verified)
  const int orow0 = m0 + wm * 64 + (lane >> 4) * 4;
  const int ocol0 = n0 + wn * 64 + fr;
  #pragma unroll
  for (int n = 0; n < 4; ++n) {
    int col = ocol0 + n * 16;
    float bv = bias[col];
    #pragma unroll
    for (int m = 0; m < 4; ++m) {
      #pragma unroll
      for (int r = 0; r < 4; ++r) {
        float v = acc[m][n][r] + bv;
        size_t idx = (size_t)(orow0 + m * 16 + r) * N + col;
        if (C_BF16) ((__bf16*)Cout)[idx] = (__bf16)v;
        else        ((float*)Cout)[idx]  = v;
      }
    }
  }
}

// ---------------- V transpose: mixed V-slice -> vbuf[bn][d][t] ----------------
__global__ __launch_bounds__(256, 2)
void vtrans(const __bf16* __restrict__ mixed, __bf16* __restrict__ vbuf) {
  const int tid = threadIdx.x;
  const int bn = blockIdx.x;          // b*16 + n
  const int b = bn >> 4, n = bn & 15;
  const int t0 = blockIdx.y * 128;
  __shared__ __bf16 tile[128][128];   // swizzled: chunk ^= (row>>3)&7

  #pragma unroll
  for (int q = 0; q < 8; ++q) {
    int lin = q * 256 + tid;
    int r = lin >> 4, ch = lin & 15;
    bf16x8 v = *(const bf16x8*)(mixed + (size_t)(t0 + r) * 12288 + (size_t)b * 6144 + n * 384 + 256 + ch * 8);
    int sch = ch ^ ((r >> 3) & 7);
    *(bf16x8*)((char*)tile + r * 256 + sch * 16) = v;
  }
  __syncthreads();
  #pragma unroll
  for (int q = 0; q < 8; ++q) {
    int lin = q * 256 + tid;
    int d = lin >> 4, tc = (lin & 15) * 8;
    bf16x8 v;
    #pragma unroll
    for (int j = 0; j < 8; ++j) {
      int row = tc + j;
      int swb = (d * 2) ^ (((row >> 3) & 7) << 4);
      v[j] = *(const __bf16*)((const char*)tile + row * 256 + swb);
    }
    *(bf16x8*)(vbuf + ((size_t)bn * 128 + d) * 2048 + t0 + tc) = v;
  }
}

// ---------------- flash attention ----------------
// grid (16 qtiles, 32 bn); 4 waves; wave owns 32 q-rows. Q in regs.
// K: [64][128] LDS, V^T: [128][64] LDS, P: per-wave [32][64] LDS.
// All tiles XOR-swizzled (byte ^= (row&7)<<4) via pre-swizzled global src.
struct SmemKVP { __bf16 k[64][128]; __bf16 v[128][64]; __bf16 p[4][32][64]; };
union  SmemU   { __bf16 q[128][128]; SmemKVP s; };

__global__ __launch_bounds__(256, 2)
void attn_kernel(const __bf16* __restrict__ mixed, const __bf16* __restrict__ vbuf,
                 __bf16* __restrict__ ctx) {
  const int tid = threadIdx.x, lane = tid & 63, w = tid >> 6;
  const int qt = blockIdx.x, bn = blockIdx.y;
  const int b = bn >> 4, n = bn & 15;
  const int qs = qt * 128;
  const int fr = lane & 15, g = lane >> 4;

  __shared__ SmemU sm;

  // ---- stage Q [128][128] (pre-swizzled source), hoist to registers ----
  #pragma unroll
  for (int qq = 0; qq < 8; ++qq) {
    int t = qq * 256 + tid;
    int r = t >> 4, ch = t & 15;
    int sch = ch ^ (r & 7);
    const __bf16* gq = mixed + (size_t)(qs + r) * 12288 + (size_t)b * 6144 + n * 384 + sch * 8;
    g2l16(gq, (char*)sm.q + qq * 4096 + w * 1024);
  }
  asm volatile("s_waitcnt vmcnt(0)" ::: "memory");
  __syncthreads();

  bf16x8 qf[2][4];
  #pragma unroll
  for (int fm = 0; fm < 2; ++fm) {
    int row = w * 32 + fm * 16 + fr;
    #pragma unroll
    for (int ks = 0; ks < 4; ++ks) {
      int ch = (ks * 4 + g) ^ (row & 7);
      qf[fm][ks] = *(const bf16x8*)((const char*)sm.q + row * 256 + ch * 16);
    }
  }
  __syncthreads();   // union reuse: all waves done reading Q

  f32x4 O[2][8] = {};
  float mrun[2][4], lrun[2][4];
  #pragma unroll
  for (int i = 0; i < 2; ++i)
    #pragma unroll
    for (int j = 0; j < 4; ++j) { mrun[i][j] = -1e30f; lrun[i][j] = 0.f; }

  const int nt = (qs + 128) >> 6;
  const __bf16* vb = vbuf + (size_t)bn * 128 * 2048;
  char* pbase = (char*)sm.s.p + w * 4096;

  for (int it = 0; it < nt; ++it) {
    const int k0 = it * 64;
    // stage K [64][128] and V^T [128][64], pre-swizzled global source
    #pragma unroll
    for (int qq = 0; qq < 4; ++qq) {
      int t = qq * 256 + tid;
      int r = t >> 4, ch = (t & 15) ^ ((t >> 4) & 7);
      const __bf16* gk = mixed + (size_t)(k0 + r) * 12288 + (size_t)b * 6144 + n * 384 + 128 + ch * 8;
      g2l16(gk, (char*)sm.s.k + qq * 4096 + w * 1024);
    }
    #pragma unroll
    for (int qq = 0; qq < 4; ++qq) {
      int t = qq * 256 + tid;
      int d = t >> 3, i = (t & 7) ^ (d & 7);
      const __bf16* gv = vb + (size_t)d * 2048 + k0 + i * 8;
      g2l16(gv, (char*)sm.s.v + qq * 4096 + w * 1024);
    }
    asm volatile("s_waitcnt vmcnt(0)" ::: "memory");
    __syncthreads();

    // ---- QK^T: S[32 q][64 kv] per wave ----
    f32x4 S[2][4] = {};
    #pragma unroll
    for (int ks = 0; ks < 4; ++ks) {
      bf16x8 kf[4];
      #pragma unroll
      for (int fn = 0; fn < 4; ++fn) {
        int row = fn * 16 + fr;
        int ch = (ks * 4 + g) ^ (row & 7);
        kf[fn] = *(const bf16x8*)((const char*)sm.s.k + row * 256 + ch * 16);
      }
      #pragma unroll
      for (int fm = 0; fm < 2; ++fm)
        #pragma unroll
        for (int fn = 0; fn < 4; ++fn)
          S[fm][fn] = __builtin_amdgcn_mfma_f32_16x16x32_bf16(qf[fm][ks], kf[fn], S[fm][fn], 0, 0, 0);
    }

    // scale + causal mask
    const float sc = 0.08838834764831845f;   // 1/sqrt(128)
    const bool needmask = (k0 + 63 > qs + w * 32);
    #pragma unroll
    for (int fm = 0; fm < 2; ++fm)
      #pragma unroll
      for (int fn = 0; fn < 4; ++fn)
        #pragma unroll
        for (int r = 0; r < 4; ++r) {
          float v = S[fm][fn][r] * sc;
          if (needmask) {
            int qrow = qs + w * 32 + fm * 16 + g * 4 + r;
            int kcol = k0 + fn * 16 + fr;
            if (kcol > qrow) v = -1e30f;
          }
          S[fm][fn][r] = v;
        }

    // ---- online softmax (wave-parallel, 16-lane shfl_xor reductions) ----
    #pragma unroll
    for (int fm = 0; fm < 2; ++fm)
      #pragma unroll
      for (int r = 0; r < 4; ++r) {
        float mx = fmaxf(fmaxf(S[fm][0][r], S[fm][1][r]), fmaxf(S[fm][2][r], S[fm][3][r]));
        #pragma unroll
        for (int off = 1; off < 16; off <<= 1)
          mx = fmaxf(mx, __shfl_xor(mx, off));
        float mnew = fmaxf(mrun[fm][r], mx);
        float scal = __expf(mrun[fm][r] - mnew);
        mrun[fm][r] = mnew;
        float rs = 0.f;
        #pragma unroll
        for (int fn = 0; fn < 4; ++fn) {
          float p = __expf(S[fm][fn][r] - mnew);
          S[fm][fn][r] = p;
          rs += p;
        }
        #pragma unroll
        for (int off = 1; off < 16; off <<= 1)
          rs += __shfl_xor(rs, off);
        lrun[fm][r] = lrun[fm][r] * scal + rs;
        #pragma unroll
        for (int fn2 = 0; fn2 < 8; ++fn2)
          O[fm][fn2][r] *= scal;
      }

    // ---- P -> LDS (per-wave private, swizzled) ----
    #pragma unroll
    for (int fm = 0; fm < 2; ++fm)
      #pragma unroll
      for (int fn = 0; fn < 4; ++fn)
        #pragma unroll
        for (int r = 0; r < 4; ++r) {
          int row = fm * 16 + g * 4 + r;
          int colb = (fn * 16 + fr) * 2;
          *(__bf16*)(pbase + row * 128 + (colb ^ ((row & 7) << 4))) = (__bf16)S[fm][fn][r];
        }

    // ---- PV: O += P * V ----
    #pragma unroll
    for (int ks2 = 0; ks2 < 2; ++ks2) {
      bf16x8 pa[2];
      #pragma unroll
      for (int fm = 0; fm < 2; ++fm) {
        int row = fm * 16 + fr;
        int ch = (ks2 * 4 + g) ^ (row & 7);
        pa[fm] = *(const bf16x8*)(pbase + row * 128 + ch * 16);
      }
      #pragma unroll
      for (int fn2 = 0; fn2 < 8; ++fn2) {
        int vrow = fn2 * 16 + fr;
        int ch = (ks2 * 4 + g) ^ (vrow & 7);
        bf16x8 vf = *(const bf16x8*)((const char*)sm.s.v + vrow * 128 + ch * 16);
        #pragma unroll
        for (int fm = 0; fm < 2; ++fm)
          O[fm][fn2] = __builtin_amdgcn_mfma_f32_16x16x32_bf16(pa[fm], vf, O[fm][fn2], 0, 0, 0);
      }
    }
    __syncthreads();   // all waves done with K/V before next stage
  }

  // ---- epilogue: ctx[m][h] bf16 ----
  #pragma unroll
  for (int fm = 0; fm < 2; ++fm)
    #pragma unroll
    for (int r = 0; r < 4; ++r) {
      int qrow = qs + w * 32 + fm * 16 + g * 4 + r;
      float inv = 1.f / lrun[fm][r];
      size_t rowb = ((size_t)qrow * 2 + b) * 2048 + n * 128;
      #pragma unroll
      for (int fn2 = 0; fn2 < 8; ++fn2)
        ctx[rowb + fn2 * 16 + fr] = (__bf16)(O[fm][fn2][r] * inv);
    }
}

extern "C" void kernel_launch(void* const* d_in, const int* in_sizes, int n_in,
                              void* d_out, int out_size, void* d_ws, size_t ws_size,
                              hipStream_t stream) {
  const float* x    = (const float*)d_in[0];
  // d_in[1] = mask: structurally causal, applied analytically in attn_kernel
  const float* wqkv = (const float*)d_in[2];
  const float* bqkv = (const float*)d_in[3];
  const float* wd   = (const float*)d_in[4];
  const float* bd   = (const float*)d_in[5];

  char* ws = (char*)d_ws;
  __bf16* xb    = (__bf16*)(ws);                 // 16.8MB (reused as ctx later)
  __bf16* wqkvb = (__bf16*)(ws + 16777216);      // 25.2MB
  __bf16* wdb   = (__bf16*)(ws + 41943040);      // 8.4MB
  __bf16* mixed = (__bf16*)(ws + 50331648);      // 50.3MB
  __bf16* vbuf  = (__bf16*)(ws + 100663296);     // 16.8MB  (total 117.4MB)
  __bf16* ctx   = xb;                            // xb dead after QKV GEMM

  cvt_kernel<<<dim3(8192),  256, 0, stream>>>(x,    xb,    2097152);
  cvt_kernel<<<dim3(12288), 256, 0, stream>>>(wqkv, wqkvb, 3145728);
  cvt_kernel<<<dim3(4096),  256, 0, stream>>>(wd,   wdb,   1048576);

  gemm_bt<1><<<dim3(48, 32), 256, 0, stream>>>(xb, wqkvb, bqkv, (void*)mixed, MROWS, NQKV, 2048);
  vtrans<<<dim3(32, 16), 256, 0, stream>>>(mixed, vbuf);
  attn_kernel<<<dim3(16, 32), 256, 0, stream>>>(mixed, vbuf, ctx);
  gemm_bt<0><<<dim3(16, 32), 256, 0, stream>>>(ctx, wdb, bd, d_out, MROWS, 2048, 2048);
}

// Round 2
// 298.280 us; speedup vs baseline: 1.2338x; 1.2338x over previous
//
#include <hip/hip_runtime.h>
#include <hip/hip_bf16.h>

// Fused attention block: QKV proj -> causal MHA -> dense proj.
// SEQ=2048, BATCH=2, HIDDEN=2048, HEADS=16, HEAD_DIM=128.
// R2: attn rewritten — mirrored-tile-pair load balance (every block = 34 KV
// iters exactly, LDS-pinned 1 block/CU), double-buffered K/V prefetch
// (T3-min: one vmcnt(0)+barrier per tile, loads fly under compute),
// 8 waves x 16 q-rows, setprio around MFMA.

typedef __bf16 bf16x8 __attribute__((ext_vector_type(8)));
typedef __bf16 bf16x4 __attribute__((ext_vector_type(4)));
typedef float  f32x4  __attribute__((ext_vector_type(4)));

#define MROWS 4096   // SEQ*BATCH
#define NQKV  6144   // 3*HIDDEN

__device__ __forceinline__ void g2l16(const void* g, void* l) {
  __builtin_amdgcn_global_load_lds(
      (const __attribute__((address_space(1))) unsigned int*)g,
      (__attribute__((address_space(3))) unsigned int*)l, 16, 0, 0);
}

// ---------------- fp32 -> bf16 convert ----------------
__global__ void cvt_kernel(const float* __restrict__ in, __bf16* __restrict__ out, int n4) {
  int i = blockIdx.x * 256 + threadIdx.x;
  if (i < n4) {
    float4 v = ((const float4*)in)[i];
    bf16x4 o = { (__bf16)v.x, (__bf16)v.y, (__bf16)v.z, (__bf16)v.w };
    ((bf16x4*)out)[i] = o;
  }
}

// ---------------- GEMM: C[M][N] = A[M][K] * B[N][K]^T + bias ----------------
// m97 structure: 128x128 tile, BK=32, 4 waves (2x2), double-buffered LDS,
// global_load_lds width=16 staging. A,B both K-contiguous bf16.
template<int C_BF16>
__global__ __launch_bounds__(256, 2)
void gemm_bt(const __bf16* __restrict__ A, const __bf16* __restrict__ B,
             const float* __restrict__ bias, void* __restrict__ Cout,
             int M, int N, int K) {
  const int tid = threadIdx.x;
  const int lane = tid & 63;
  const int w  = tid >> 6;
  const int wm = w >> 1, wn = w & 1;
  const int m0 = blockIdx.y * 128, n0 = blockIdx.x * 128;
  const int fr = lane & 15, fh = (lane >> 4) * 8;

  __shared__ __bf16 As[2][128][32];
  __shared__ __bf16 Bs[2][128][32];

  f32x4 acc[4][4] = {};

  const int srow = tid >> 2;        // staging row within 64-row half
  const int scb  = (tid & 3) * 8;   // staging k-offset (8 bf16 = 16B)

  {
    #pragma unroll
    for (int q = 0; q < 2; ++q) {
      int row = q * 64 + srow;
      g2l16(A + (size_t)(m0 + row) * K + scb,
            (char*)&As[0][0][0] + (q * 4 + w) * 1024);
      g2l16(B + (size_t)(n0 + row) * K + scb,
            (char*)&Bs[0][0][0] + (q * 4 + w) * 1024);
    }
  }
  asm volatile("s_waitcnt vmcnt(0)" ::: "memory");
  __syncthreads();

  const int KT = K >> 5;
  int buf = 0;
  for (int kt = 0; kt < KT; ++kt) {
    if (kt + 1 < KT) {
      const int k0 = (kt + 1) << 5;
      #pragma unroll
      for (int q = 0; q < 2; ++q) {
        int row = q * 64 + srow;
        g2l16(A + (size_t)(m0 + row) * K + k0 + scb,
              (char*)&As[buf ^ 1][0][0] + (q * 4 + w) * 1024);
        g2l16(B + (size_t)(n0 + row) * K + k0 + scb,
              (char*)&Bs[buf ^ 1][0][0] + (q * 4 + w) * 1024);
      }
    }
    bf16x8 af[4], bfr[4];
    #pragma unroll
    for (int m = 0; m < 4; ++m)
      af[m] = *(const bf16x8*)&As[buf][wm * 64 + m * 16 + fr][fh];
    #pragma unroll
    for (int n = 0; n < 4; ++n)
      bfr[n] = *(const bf16x8*)&Bs[buf][wn * 64 + n * 16 + fr][fh];
    #pragma unroll
    for (int m = 0; m < 4; ++m)
      #pragma unroll
      for (int n = 0; n < 4; ++n)
        acc[m][n] = __builtin_amdgcn_mfma_f32_16x16x32_bf16(af[m], bfr[n], acc[m][n], 0, 0, 0);
    __syncthreads();
    buf ^= 1;
  }

  // epilogue: C/D layout col=lane&15, row=(lane>>4)*4+reg  (m89/m91-verified)
  const int orow0 = m0 + wm * 64 + (lane >> 4) * 4;
  const int ocol0 = n0 + wn * 64 + fr;
  #pragma unroll
  for (int n = 0; n < 4; ++n) {
    int col = ocol0 + n * 16;
    float bv = bias[col];
    #pragma unroll
    for (int m = 0; m < 4; ++m) {
      #pragma unroll
      for (int r = 0; r < 4; ++r) {
        float v = acc[m][n][r] + bv;
        size_t idx = (size_t)(orow0 + m * 16 + r) * N + col;
        if (C_BF16) ((__bf16*)Cout)[idx] = (__bf16)v;
        else        ((float*)Cout)[idx]  = v;
      }
    }
  }
}

// ---------------- V transpose: mixed V-slice -> vbuf[bn][d][t] ----------------
__global__ __launch_bounds__(256, 2)
void vtrans(const __bf16* __restrict__ mixed, __bf16* __restrict__ vbuf) {
  const int tid = threadIdx.x;
  const int bn = blockIdx.x;          // b*16 + n
  const int b = bn >> 4, n = bn & 15;
  const int t0 = blockIdx.y * 128;
  __shared__ __bf16 tile[128][128];   // swizzled: chunk ^= (row>>3)&7

  #pragma unroll
  for (int q = 0; q < 8; ++q) {
    int lin = q * 256 + tid;
    int r = lin >> 4, ch = lin & 15;
    bf16x8 v = *(const bf16x8*)(mixed + (size_t)(t0 + r) * 12288 + (size_t)b * 6144 + n * 384 + 256 + ch * 8);
    int sch = ch ^ ((r >> 3) & 7);
    *(bf16x8*)((char*)tile + r * 256 + sch * 16) = v;
  }
  __syncthreads();
  #pragma unroll
  for (int q = 0; q < 8; ++q) {
    int lin = q * 256 + tid;
    int d = lin >> 4, tc = (lin & 15) * 8;
    bf16x8 v;
    #pragma unroll
    for (int j = 0; j < 8; ++j) {
      int row = tc + j;
      int swb = (d * 2) ^ (((row >> 3) & 7) << 4);
      v[j] = *(const __bf16*)((const char*)tile + row * 256 + swb);
    }
    *(bf16x8*)(vbuf + ((size_t)bn * 128 + d) * 2048 + t0 + tc) = v;
  }
}

// ---------------- flash attention ----------------
// grid (8 pairs, 32 bn); 512 threads = 8 waves x 16 q-rows. Each block
// processes mirrored q-tiles (15-x) then (x): exactly 34 KV iters per block.
// LDS 84KB pins 1 block/CU -> deterministic 1:1 block->CU balance.
// K/V double-buffered: issue tile t+1 after the single vmcnt(0)+barrier,
// compute tile t underneath (T3-min).
struct SmemA {
  __bf16 k[2][64][128];   // 32KB  (aliased by Q staging area)
  __bf16 v[2][128][64];   // 32KB
  __bf16 p[8][16][64];    // 16KB per-wave private P
};
union SmemUA { __bf16 q[128][128]; SmemA s; char pad[86016]; };

__global__ __launch_bounds__(512, 1)
void attn_kernel(const __bf16* __restrict__ mixed, const __bf16* __restrict__ vbuf,
                 __bf16* __restrict__ ctx) {
  const int tid = threadIdx.x, lane = tid & 63, w = tid >> 6;   // w in 0..7
  const int bn = blockIdx.y;
  const int b = bn >> 4, n = bn & 15;
  const int fr = lane & 15, g = lane >> 4;

  __shared__ SmemUA sm;
  const __bf16* vb = vbuf + (size_t)bn * 128 * 2048;
  const __bf16* mixb = mixed + (size_t)b * 6144 + n * 384;
  char* pbase = (char*)sm.s.p + w * 2048;

  auto stage_kv = [&](int k0, int buf) {
    #pragma unroll
    for (int qq = 0; qq < 2; ++qq) {
      int t = qq * 512 + tid;
      int r = t >> 4, ch = (t & 15) ^ (r & 7);
      g2l16(mixb + (size_t)(k0 + r) * 12288 + 128 + ch * 8,
            (char*)sm.s.k[buf] + qq * 8192 + w * 1024);
    }
    #pragma unroll
    for (int qq = 0; qq < 2; ++qq) {
      int t = qq * 512 + tid;
      int d = t >> 3, i = (t & 7) ^ (d & 7);
      g2l16(vb + (size_t)d * 2048 + k0 + i * 8,
            (char*)sm.s.v[buf] + qq * 8192 + w * 1024);
    }
  };

  #pragma unroll 1
  for (int phase = 0; phase < 2; ++phase) {
    const int qt = phase ? (int)blockIdx.x : (15 - (int)blockIdx.x);  // heavy first
    const int qs = qt * 128;

    __syncthreads();   // prior phase fully done before Q restage (aliases K dbuf)

    // ---- stage Q [128][128] (pre-swizzled source) ----
    #pragma unroll
    for (int qq = 0; qq < 4; ++qq) {
      int t = qq * 512 + tid;
      int r = t >> 4, ch = (t & 15) ^ (r & 7);
      g2l16(mixb + (size_t)(qs + r) * 12288 + ch * 8,
            (char*)sm.q + qq * 8192 + w * 1024);
    }
    asm volatile("s_waitcnt vmcnt(0)" ::: "memory");
    __syncthreads();

    bf16x8 qf[4];
    {
      const int row = w * 16 + fr;
      #pragma unroll
      for (int ks = 0; ks < 4; ++ks) {
        int ch = (ks * 4 + g) ^ (row & 7);
        qf[ks] = *(const bf16x8*)((const char*)sm.q + row * 256 + ch * 16);
      }
    }
    asm volatile("s_waitcnt lgkmcnt(0)" ::: "memory");
    __syncthreads();   // all qf reads landed before K staging overwrites Q area

    f32x4 O[8] = {};
    float mrun[4], lrun[4];
    #pragma unroll
    for (int j = 0; j < 4; ++j) { mrun[j] = -1e30f; lrun[j] = 0.f; }

    const int nt = (qs + 128) >> 6;
    int cur = 0;
    stage_kv(0, 0);

    #pragma unroll 1
    for (int it = 0; it < nt; ++it) {
      const int k0 = it * 64;
      asm volatile("s_waitcnt vmcnt(0)" ::: "memory");   // buf[cur] landed
      __syncthreads();                                    // ...for ALL waves
      if (it + 1 < nt) stage_kv((it + 1) * 64, cur ^ 1);  // fly under compute

      // ---- QK^T: S[16 q][64 kv] per wave ----
      f32x4 S[4] = {};
      __builtin_amdgcn_s_setprio(1);
      #pragma unroll
      for (int ks = 0; ks < 4; ++ks) {
        bf16x8 kf[4];
        #pragma unroll
        for (int fn = 0; fn < 4; ++fn) {
          int row = fn * 16 + fr;
          int ch = (ks * 4 + g) ^ (row & 7);
          kf[fn] = *(const bf16x8*)((const char*)sm.s.k[cur] + row * 256 + ch * 16);
        }
        #pragma unroll
        for (int fn = 0; fn < 4; ++fn)
          S[fn] = __builtin_amdgcn_mfma_f32_16x16x32_bf16(qf[ks], kf[fn], S[fn], 0, 0, 0);
      }
      __builtin_amdgcn_s_setprio(0);

      // scale + causal mask
      const float sc = 0.08838834764831845f;   // 1/sqrt(128)
      const bool needmask = (k0 + 63 > qs + w * 16);
      #pragma unroll
      for (int fn = 0; fn < 4; ++fn)
        #pragma unroll
        for (int r = 0; r < 4; ++r) {
          float v = S[fn][r] * sc;
          if (needmask) {
            int qrow = qs + w * 16 + g * 4 + r;
            int kcol = k0 + fn * 16 + fr;
            if (kcol > qrow) v = -1e30f;
          }
          S[fn][r] = v;
        }

      // ---- online softmax (16-lane shfl_xor reductions) ----
      #pragma unroll
      for (int r = 0; r < 4; ++r) {
        float mx = fmaxf(fmaxf(S[0][r], S[1][r]), fmaxf(S[2][r], S[3][r]));
        #pragma unroll
        for (int off = 1; off < 16; off <<= 1)
          mx = fmaxf(mx, __shfl_xor(mx, off));
        float mnew = fmaxf(mrun[r], mx);
        float scal = __expf(mrun[r] - mnew);
        mrun[r] = mnew;
        float rs = 0.f;
        #pragma unroll
        for (int fn = 0; fn < 4; ++fn) {
          float p = __expf(S[fn][r] - mnew);
          S[fn][r] = p;
          rs += p;
        }
        #pragma unroll
        for (int off = 1; off < 16; off <<= 1)
          rs += __shfl_xor(rs, off);
        lrun[r] = lrun[r] * scal + rs;
        #pragma unroll
        for (int fn2 = 0; fn2 < 8; ++fn2)
          O[fn2][r] *= scal;
      }

      // ---- P -> LDS (per-wave private, swizzled) ----
      #pragma unroll
      for (int fn = 0; fn < 4; ++fn)
        #pragma unroll
        for (int r = 0; r < 4; ++r) {
          int prow = g * 4 + r;
          int colb = (fn * 16 + fr) * 2;
          *(__bf16*)(pbase + prow * 128 + (colb ^ ((prow & 7) << 4))) = (__bf16)S[fn][r];
        }

      // ---- PV: O += P * V ----
      __builtin_amdgcn_s_setprio(1);
      #pragma unroll
      for (int ks2 = 0; ks2 < 2; ++ks2) {
        bf16x8 pa;
        {
          int ch = (ks2 * 4 + g) ^ (fr & 7);
          pa = *(const bf16x8*)(pbase + fr * 128 + ch * 16);
        }
        #pragma unroll
        for (int fn2 = 0; fn2 < 8; ++fn2) {
          int vrow = fn2 * 16 + fr;
          int ch = (ks2 * 4 + g) ^ (vrow & 7);
          bf16x8 vf = *(const bf16x8*)((const char*)sm.s.v[cur] + vrow * 128 + ch * 16);
          O[fn2] = __builtin_amdgcn_mfma_f32_16x16x32_bf16(pa, vf, O[fn2], 0, 0, 0);
        }
      }
      __builtin_amdgcn_s_setprio(0);
      cur ^= 1;
    }

    // ---- epilogue: ctx[m][h] bf16 ----
    #pragma unroll
    for (int r = 0; r < 4; ++r) {
      int qrow = qs + w * 16 + g * 4 + r;
      float inv = 1.f / lrun[r];
      size_t rowb = ((size_t)qrow * 2 + b) * 2048 + n * 128;
      #pragma unroll
      for (int fn2 = 0; fn2 < 8; ++fn2)
        ctx[rowb + fn2 * 16 + fr] = (__bf16)(O[fn2][r] * inv);
    }
  }
}

extern "C" void kernel_launch(void* const* d_in, const int* in_sizes, int n_in,
                              void* d_out, int out_size, void* d_ws, size_t ws_size,
                              hipStream_t stream) {
  const float* x    = (const float*)d_in[0];
  // d_in[1] = mask: structurally causal, applied analytically in attn_kernel
  const float* wqkv = (const float*)d_in[2];
  const float* bqkv = (const float*)d_in[3];
  const float* wd   = (const float*)d_in[4];
  const float* bd   = (const float*)d_in[5];

  char* ws = (char*)d_ws;
  __bf16* xb    = (__bf16*)(ws);                 // 16.8MB (reused as ctx later)
  __bf16* wqkvb = (__bf16*)(ws + 16777216);      // 25.2MB
  __bf16* wdb   = (__bf16*)(ws + 41943040);      // 8.4MB
  __bf16* mixed = (__bf16*)(ws + 50331648);      // 50.3MB
  __bf16* vbuf  = (__bf16*)(ws + 100663296);     // 16.8MB  (total 117.4MB)
  __bf16* ctx   = xb;                            // xb dead after QKV GEMM

  cvt_kernel<<<dim3(8192),  256, 0, stream>>>(x,    xb,    2097152);
  cvt_kernel<<<dim3(12288), 256, 0, stream>>>(wqkv, wqkvb, 3145728);
  cvt_kernel<<<dim3(4096),  256, 0, stream>>>(wd,   wdb,   1048576);

  gemm_bt<1><<<dim3(48, 32), 256, 0, stream>>>(xb, wqkvb, bqkv, (void*)mixed, MROWS, NQKV, 2048);
  vtrans<<<dim3(32, 16), 256, 0, stream>>>(mixed, vbuf);
  attn_kernel<<<dim3(8, 32), 512, 0, stream>>>(mixed, vbuf, ctx);
  gemm_bt<0><<<dim3(16, 32), 256, 0, stream>>>(ctx, wdb, bd, d_out, MROWS, 2048, 2048);
}

// Round 3
// 278.857 us; speedup vs baseline: 1.3198x; 1.0697x over previous
//
#include <hip/hip_runtime.h>
#include <hip/hip_bf16.h>

// Fused attention block: QKV proj -> causal MHA -> dense proj.
// SEQ=2048, BATCH=2, HIDDEN=2048, HEADS=16, HEAD_DIM=128.
// R3: GEMMs ported to the 8-phase counted-vmcnt 256-wide template (T3+T4)
// with T2 LDS XOR-swizzle via pre-swizzled global source and T5 setprio.
// QKV: BM=256 (m201 geometry). Dense: BM=128 (256 blocks = 1/CU packed).

typedef __bf16 bf16x8 __attribute__((ext_vector_type(8)));
typedef __bf16 bf16x4 __attribute__((ext_vector_type(4)));
typedef float  f32x4  __attribute__((ext_vector_type(4)));

#define MROWS 4096   // SEQ*BATCH
#define NQKV  6144   // 3*HIDDEN

__device__ __forceinline__ void g2l16(const void* g, void* l) {
  __builtin_amdgcn_global_load_lds(
      (const __attribute__((address_space(1))) unsigned int*)g,
      (__attribute__((address_space(3))) unsigned int*)l, 16, 0, 0);
}

// ---------------- fp32 -> bf16 convert ----------------
__global__ void cvt_kernel(const float* __restrict__ in, __bf16* __restrict__ out, int n4) {
  int i = blockIdx.x * 256 + threadIdx.x;
  if (i < n4) {
    float4 v = ((const float4*)in)[i];
    bf16x4 o = { (__bf16)v.x, (__bf16)v.y, (__bf16)v.z, (__bf16)v.w };
    ((bf16x4*)out)[i] = o;
  }
}

// ---------------- 8-phase GEMM: C[M][N] = A[M][K] * B[N][K]^T + bias --------
// BMxBN=MHALF*64 x 256, BK=64, 8 waves (2M x 4N), 512 threads.
// Regions per K-tile: A-q{0,1} (64-row quadrant strips), B-q{0,1} (32-col).
// Phase p computes one C-quadrant (Gray order); stage region(kt+2) one phase
// after region(kt)'s last LDS read; one vmcnt(VW) per tile at ph3 before the
// final barrier (per-wave count made collective by the barrier).
// LDS content swizzled chunk^=(row&7) via pre-swizzled GLOBAL source (g2l16
// writes linearly); ds_read applies the same XOR -> conflict-free b128 reads.
#define DO_MFMA(MH, NH, BV)                                                     \
  _Pragma("unroll")                                                             \
  for (int mf = 0; mf < MHALF; ++mf) {                                          \
    _Pragma("unroll")                                                           \
    for (int nf = 0; nf < 2; ++nf) {                                            \
      f32x4& a0 = acc[(MH)*MHALF + mf][(NH)*2 + nf];                            \
      a0 = __builtin_amdgcn_mfma_f32_16x16x32_bf16(afr[mf][0], BV[nf][0], a0, 0,0,0); \
      a0 = __builtin_amdgcn_mfma_f32_16x16x32_bf16(afr[mf][1], BV[nf][1], a0, 0,0,0); \
    }                                                                           \
  }

template<int MHALF, int C_BF16>   // MHALF=4 -> BM=256 ; MHALF=2 -> BM=128
__global__ __launch_bounds__(512, 2)
void gemm8(const __bf16* __restrict__ A, const __bf16* __restrict__ B,
           const float* __restrict__ bias, void* __restrict__ Cout,
           int M, int N, int K) {
  constexpr int BM = MHALF * 64;
  constexpr int ABYTES = BM * 128;      // A tile bytes (BM x 64 bf16)
  constexpr int LA = BM / 128;          // A stage instrs per thread per region
  constexpr int BMQ = BM / 4;           // rows per A quadrant strip
  constexpr int UPS = BMQ / 8;          // 1KB staging units per A strip

  const int tid = threadIdx.x, lane = tid & 63, w = tid >> 6;
  const int wm = w >> 2, wn = w & 3;
  const int m0 = blockIdx.y * BM, n0 = blockIdx.x * 256;
  const int fr = lane & 15, g = lane >> 4;
  const int r_off = lane >> 3;                  // staging: row within 8-row unit
  const int swch = (lane & 7) ^ r_off;          // pre-swizzled global chunk

  __shared__ char smem[2][ABYTES + 32768];      // [buf][A | B(32KB)]

  f32x4 acc[2*MHALF][4] = {};
  bf16x8 afr[MHALF][2];                         // current m-half A frags
  bf16x8 b0[2][2], b1[2][2];                    // B nh0 (held all tile), nh1

  const int nt = K >> 6;

  auto stageA = [&](int kt2, int mq) {
    char* base = smem[kt2 & 1];
    #pragma unroll
    for (int q = 0; q < LA; ++q) {
      int u = q*8 + w;
      int strip = u / UPS;                       // 0..1 (= A half)
      int rih = mq*BMQ + (u % UPS)*8;            // row-in-half base of unit
      g2l16(A + (size_t)(m0 + strip*(BM/2) + rih + r_off) * K + kt2*64 + swch*8,
            base + (strip*(BM/2) + rih)*128);
    }
  };
  auto stageB = [&](int kt2, int nq) {
    char* base = smem[kt2 & 1] + ABYTES;
    #pragma unroll
    for (int q = 0; q < 2; ++q) {
      int u = q*8 + w;
      int strip = u >> 2;                        // 0..3 (64-row groups)
      int ris = (u & 3)*8;
      g2l16(B + (size_t)(n0 + strip*64 + nq*32 + ris + r_off) * K + kt2*64 + swch*8,
            base + (strip >> 1)*16384 + ((strip & 1)*64 + nq*32 + ris)*128);
    }
  };
  auto loadA = [&](int kt, int mh) {
    const char* ah = smem[kt & 1] + wm*(BM/2)*128;
    #pragma unroll
    for (int mf = 0; mf < MHALF; ++mf) {
      int row = (mh*MHALF + mf)*16 + fr;
      #pragma unroll
      for (int ks = 0; ks < 2; ++ks)
        afr[mf][ks] = *(const bf16x8*)(ah + row*128 + (((ks*4+g) ^ (row & 7)) << 4));
    }
  };
  auto loadB = [&](int kt, int nh, bf16x8 (&bv)[2][2]) {
    const char* bh = smem[kt & 1] + ABYTES + (wn >> 1)*16384;
    #pragma unroll
    for (int nf = 0; nf < 2; ++nf) {
      int row = (wn & 1)*64 + nh*32 + nf*16 + fr;
      #pragma unroll
      for (int ks = 0; ks < 2; ++ks)
        bv[nf][ks] = *(const bf16x8*)(bh + row*128 + (((ks*4+g) ^ (row & 7)) << 4));
    }
  };

  // prologue: tiles 0,1 in steady-state issue order
  stageA(0,0); stageB(0,0); stageB(0,1); stageA(0,1);
  stageA(1,0); stageB(1,0); stageB(1,1); stageA(1,1);
  if constexpr (MHALF == 4) asm volatile("s_waitcnt vmcnt(8)" ::: "memory");
  else                      asm volatile("s_waitcnt vmcnt(6)" ::: "memory");
  asm volatile("s_barrier" ::: "memory");

  for (int kt = 0; kt < nt; ++kt) {
    // kt+2 >= nt stages are phantoms: they read adjacent mapped ws buffers and
    // land in regions never read again -- keeps vmcnt counts uniform.
    // ph0: read A(mh0)+B(nh0)
    loadA(kt, 0); loadB(kt, 0, b0);
    asm volatile("s_barrier" ::: "memory");
    __builtin_amdgcn_s_setprio(1);
    DO_MFMA(0,0,b0)
    __builtin_amdgcn_s_setprio(0);
    asm volatile("s_barrier" ::: "memory");
    // ph1: read B(nh1); stage A-q0, B-q0 of kt+2 (their kt-reads done at ph0)
    loadB(kt, 1, b1);
    stageA(kt+2, 0); stageB(kt+2, 0);
    asm volatile("s_barrier" ::: "memory");
    __builtin_amdgcn_s_setprio(1);
    DO_MFMA(0,1,b1)
    __builtin_amdgcn_s_setprio(0);
    asm volatile("s_barrier" ::: "memory");
    // ph2: read A(mh1); stage B-q1 (last read ph1)
    loadA(kt, 1);
    stageB(kt+2, 1);
    asm volatile("s_barrier" ::: "memory");
    __builtin_amdgcn_s_setprio(1);
    DO_MFMA(1,1,b1)
    __builtin_amdgcn_s_setprio(0);
    asm volatile("s_barrier" ::: "memory");
    // ph3: no reads (b0 held in regs); stage A-q1 (last read ph2);
    // then wait tile kt+1 fully landed (per-wave) + barrier (collective).
    stageA(kt+2, 1);
    asm volatile("s_barrier" ::: "memory");
    __builtin_amdgcn_s_setprio(1);
    DO_MFMA(1,0,b0)
    __builtin_amdgcn_s_setprio(0);
    if constexpr (MHALF == 4) asm volatile("s_waitcnt vmcnt(8)" ::: "memory");
    else                      asm volatile("s_waitcnt vmcnt(6)" ::: "memory");
    asm volatile("s_barrier" ::: "memory");
  }

  // epilogue: C/D layout col=lane&15, row=(lane>>4)*4+reg (m89/m91-verified)
  const int orow0 = m0 + wm*(BM/2) + g*4;
  const int ocol0 = n0 + wn*64 + fr;
  #pragma unroll
  for (int nf = 0; nf < 4; ++nf) {
    int col = ocol0 + nf*16;
    float bv = bias[col];
    #pragma unroll
    for (int mf = 0; mf < 2*MHALF; ++mf) {
      #pragma unroll
      for (int r = 0; r < 4; ++r) {
        float v = acc[mf][nf][r] + bv;
        size_t idx = (size_t)(orow0 + mf*16 + r) * N + col;
        if (C_BF16) ((__bf16*)Cout)[idx] = (__bf16)v;
        else        ((float*)Cout)[idx]  = v;
      }
    }
  }
}

// ---------------- V transpose: mixed V-slice -> vbuf[bn][d][t] ----------------
__global__ __launch_bounds__(256, 2)
void vtrans(const __bf16* __restrict__ mixed, __bf16* __restrict__ vbuf) {
  const int tid = threadIdx.x;
  const int bn = blockIdx.x;          // b*16 + n
  const int b = bn >> 4, n = bn & 15;
  const int t0 = blockIdx.y * 128;
  __shared__ __bf16 tile[128][128];   // swizzled: chunk ^= (row>>3)&7

  #pragma unroll
  for (int q = 0; q < 8; ++q) {
    int lin = q * 256 + tid;
    int r = lin >> 4, ch = lin & 15;
    bf16x8 v = *(const bf16x8*)(mixed + (size_t)(t0 + r) * 12288 + (size_t)b * 6144 + n * 384 + 256 + ch * 8);
    int sch = ch ^ ((r >> 3) & 7);
    *(bf16x8*)((char*)tile + r * 256 + sch * 16) = v;
  }
  __syncthreads();
  #pragma unroll
  for (int q = 0; q < 8; ++q) {
    int lin = q * 256 + tid;
    int d = lin >> 4, tc = (lin & 15) * 8;
    bf16x8 v;
    #pragma unroll
    for (int j = 0; j < 8; ++j) {
      int row = tc + j;
      int swb = (d * 2) ^ (((row >> 3) & 7) << 4);
      v[j] = *(const __bf16*)((const char*)tile + row * 256 + swb);
    }
    *(bf16x8*)(vbuf + ((size_t)bn * 128 + d) * 2048 + t0 + tc) = v;
  }
}

// ---------------- flash attention ----------------
// grid (8 pairs, 32 bn); 512 threads = 8 waves x 16 q-rows. Each block
// processes mirrored q-tiles (15-x) then (x): exactly 34 KV iters per block.
// LDS 84KB pins 1 block/CU -> deterministic 1:1 block->CU balance.
struct SmemA {
  __bf16 k[2][64][128];   // 32KB  (aliased by Q staging area)
  __bf16 v[2][128][64];   // 32KB
  __bf16 p[8][16][64];    // 16KB per-wave private P
};
union SmemUA { __bf16 q[128][128]; SmemA s; char pad[86016]; };

__global__ __launch_bounds__(512, 1)
void attn_kernel(const __bf16* __restrict__ mixed, const __bf16* __restrict__ vbuf,
                 __bf16* __restrict__ ctx) {
  const int tid = threadIdx.x, lane = tid & 63, w = tid >> 6;   // w in 0..7
  const int bn = blockIdx.y;
  const int b = bn >> 4, n = bn & 15;
  const int fr = lane & 15, g = lane >> 4;

  __shared__ SmemUA sm;
  const __bf16* vb = vbuf + (size_t)bn * 128 * 2048;
  const __bf16* mixb = mixed + (size_t)b * 6144 + n * 384;
  char* pbase = (char*)sm.s.p + w * 2048;

  auto stage_kv = [&](int k0, int buf) {
    #pragma unroll
    for (int qq = 0; qq < 2; ++qq) {
      int t = qq * 512 + tid;
      int r = t >> 4, ch = (t & 15) ^ (r & 7);
      g2l16(mixb + (size_t)(k0 + r) * 12288 + 128 + ch * 8,
            (char*)sm.s.k[buf] + qq * 8192 + w * 1024);
    }
    #pragma unroll
    for (int qq = 0; qq < 2; ++qq) {
      int t = qq * 512 + tid;
      int d = t >> 3, i = (t & 7) ^ (d & 7);
      g2l16(vb + (size_t)d * 2048 + k0 + i * 8,
            (char*)sm.s.v[buf] + qq * 8192 + w * 1024);
    }
  };

  #pragma unroll 1
  for (int phase = 0; phase < 2; ++phase) {
    const int qt = phase ? (int)blockIdx.x : (15 - (int)blockIdx.x);  // heavy first
    const int qs = qt * 128;

    __syncthreads();   // prior phase fully done before Q restage (aliases K dbuf)

    // ---- stage Q [128][128] (pre-swizzled source) ----
    #pragma unroll
    for (int qq = 0; qq < 4; ++qq) {
      int t = qq * 512 + tid;
      int r = t >> 4, ch = (t & 15) ^ (r & 7);
      g2l16(mixb + (size_t)(qs + r) * 12288 + ch * 8,
            (char*)sm.q + qq * 8192 + w * 1024);
    }
    asm volatile("s_waitcnt vmcnt(0)" ::: "memory");
    __syncthreads();

    bf16x8 qf[4];
    {
      const int row = w * 16 + fr;
      #pragma unroll
      for (int ks = 0; ks < 4; ++ks) {
        int ch = (ks * 4 + g) ^ (row & 7);
        qf[ks] = *(const bf16x8*)((const char*)sm.q + row * 256 + ch * 16);
      }
    }
    asm volatile("s_waitcnt lgkmcnt(0)" ::: "memory");
    __syncthreads();   // all qf reads landed before K staging overwrites Q area

    f32x4 O[8] = {};
    float mrun[4], lrun[4];
    #pragma unroll
    for (int j = 0; j < 4; ++j) { mrun[j] = -1e30f; lrun[j] = 0.f; }

    const int nt = (qs + 128) >> 6;
    int cur = 0;
    stage_kv(0, 0);

    #pragma unroll 1
    for (int it = 0; it < nt; ++it) {
      const int k0 = it * 64;
      asm volatile("s_waitcnt vmcnt(0)" ::: "memory");   // buf[cur] landed
      __syncthreads();                                    // ...for ALL waves
      if (it + 1 < nt) stage_kv((it + 1) * 64, cur ^ 1);  // fly under compute

      // ---- QK^T: S[16 q][64 kv] per wave ----
      f32x4 S[4] = {};
      __builtin_amdgcn_s_setprio(1);
      #pragma unroll
      for (int ks = 0; ks < 4; ++ks) {
        bf16x8 kf[4];
        #pragma unroll
        for (int fn = 0; fn < 4; ++fn) {
          int row = fn * 16 + fr;
          int ch = (ks * 4 + g) ^ (row & 7);
          kf[fn] = *(const bf16x8*)((const char*)sm.s.k[cur] + row * 256 + ch * 16);
        }
        #pragma unroll
        for (int fn = 0; fn < 4; ++fn)
          S[fn] = __builtin_amdgcn_mfma_f32_16x16x32_bf16(qf[ks], kf[fn], S[fn], 0, 0, 0);
      }
      __builtin_amdgcn_s_setprio(0);

      // scale + causal mask
      const float sc = 0.08838834764831845f;   // 1/sqrt(128)
      const bool needmask = (k0 + 63 > qs + w * 16);
      #pragma unroll
      for (int fn = 0; fn < 4; ++fn)
        #pragma unroll
        for (int r = 0; r < 4; ++r) {
          float v = S[fn][r] * sc;
          if (needmask) {
            int qrow = qs + w * 16 + g * 4 + r;
            int kcol = k0 + fn * 16 + fr;
            if (kcol > qrow) v = -1e30f;
          }
          S[fn][r] = v;
        }

      // ---- online softmax (16-lane shfl_xor reductions) ----
      #pragma unroll
      for (int r = 0; r < 4; ++r) {
        float mx = fmaxf(fmaxf(S[0][r], S[1][r]), fmaxf(S[2][r], S[3][r]));
        #pragma unroll
        for (int off = 1; off < 16; off <<= 1)
          mx = fmaxf(mx, __shfl_xor(mx, off));
        float mnew = fmaxf(mrun[r], mx);
        float scal = __expf(mrun[r] - mnew);
        mrun[r] = mnew;
        float rs = 0.f;
        #pragma unroll
        for (int fn = 0; fn < 4; ++fn) {
          float p = __expf(S[fn][r] - mnew);
          S[fn][r] = p;
          rs += p;
        }
        #pragma unroll
        for (int off = 1; off < 16; off <<= 1)
          rs += __shfl_xor(rs, off);
        lrun[r] = lrun[r] * scal + rs;
        #pragma unroll
        for (int fn2 = 0; fn2 < 8; ++fn2)
          O[fn2][r] *= scal;
      }

      // ---- P -> LDS (per-wave private, swizzled) ----
      #pragma unroll
      for (int fn = 0; fn < 4; ++fn)
        #pragma unroll
        for (int r = 0; r < 4; ++r) {
          int prow = g * 4 + r;
          int colb = (fn * 16 + fr) * 2;
          *(__bf16*)(pbase + prow * 128 + (colb ^ ((prow & 7) << 4))) = (__bf16)S[fn][r];
        }

      // ---- PV: O += P * V ----
      __builtin_amdgcn_s_setprio(1);
      #pragma unroll
      for (int ks2 = 0; ks2 < 2; ++ks2) {
        bf16x8 pa;
        {
          int ch = (ks2 * 4 + g) ^ (fr & 7);
          pa = *(const bf16x8*)(pbase + fr * 128 + ch * 16);
        }
        #pragma unroll
        for (int fn2 = 0; fn2 < 8; ++fn2) {
          int vrow = fn2 * 16 + fr;
          int ch = (ks2 * 4 + g) ^ (vrow & 7);
          bf16x8 vf = *(const bf16x8*)((const char*)sm.s.v[cur] + vrow * 128 + ch * 16);
          O[fn2] = __builtin_amdgcn_mfma_f32_16x16x32_bf16(pa, vf, O[fn2], 0, 0, 0);
        }
      }
      __builtin_amdgcn_s_setprio(0);
      cur ^= 1;
    }

    // ---- epilogue: ctx[m][h] bf16 ----
    #pragma unroll
    for (int r = 0; r < 4; ++r) {
      int qrow = qs + w * 16 + g * 4 + r;
      float inv = 1.f / lrun[r];
      size_t rowb = ((size_t)qrow * 2 + b) * 2048 + n * 128;
      #pragma unroll
      for (int fn2 = 0; fn2 < 8; ++fn2)
        ctx[rowb + fn2 * 16 + fr] = (__bf16)(O[fn2][r] * inv);
    }
  }
}

extern "C" void kernel_launch(void* const* d_in, const int* in_sizes, int n_in,
                              void* d_out, int out_size, void* d_ws, size_t ws_size,
                              hipStream_t stream) {
  const float* x    = (const float*)d_in[0];
  // d_in[1] = mask: structurally causal, applied analytically in attn_kernel
  const float* wqkv = (const float*)d_in[2];
  const float* bqkv = (const float*)d_in[3];
  const float* wd   = (const float*)d_in[4];
  const float* bd   = (const float*)d_in[5];

  char* ws = (char*)d_ws;
  __bf16* xb    = (__bf16*)(ws);                 // 16.8MB (reused as ctx later)
  __bf16* wqkvb = (__bf16*)(ws + 16777216);      // 25.2MB
  __bf16* wdb   = (__bf16*)(ws + 41943040);      // 8.4MB
  __bf16* mixed = (__bf16*)(ws + 50331648);      // 50.3MB
  __bf16* vbuf  = (__bf16*)(ws + 100663296);     // 16.8MB  (total 117.4MB)
  __bf16* ctx   = xb;                            // xb dead after QKV GEMM

  cvt_kernel<<<dim3(8192),  256, 0, stream>>>(x,    xb,    2097152);
  cvt_kernel<<<dim3(12288), 256, 0, stream>>>(wqkv, wqkvb, 3145728);
  cvt_kernel<<<dim3(4096),  256, 0, stream>>>(wd,   wdb,   1048576);

  gemm8<4,1><<<dim3(24, 16), 512, 0, stream>>>(xb, wqkvb, bqkv, (void*)mixed, MROWS, NQKV, 2048);
  vtrans<<<dim3(32, 16), 256, 0, stream>>>(mixed, vbuf);
  attn_kernel<<<dim3(8, 32), 512, 0, stream>>>(mixed, vbuf, ctx);
  gemm8<2,0><<<dim3(8, 32), 512, 0, stream>>>(ctx, wdb, bd, d_out, MROWS, 2048, 2048);
}

// Round 4
// 265.899 us; speedup vs baseline: 1.3841x; 1.0487x over previous
//
#include <hip/hip_runtime.h>
#include <hip/hip_bf16.h>

// Fused attention block: QKV proj -> causal MHA -> dense proj.
// SEQ=2048, BATCH=2, HIDDEN=2048, HEADS=16, HEAD_DIM=128.
// R4: GEMM template re-parameterized (MF x NF per-wave frags). QKV: BM=256,
// BN=192 -> 512 blocks = 2 EXACT rounds at 1 block/CU (kills the 1.5-round
// quantization loss). 2 phases/K-tile (24 MFMA clusters, B in regs), 4
// barriers/tile, region-phased depth-2 staging, vmcnt(5) once per tile.

typedef __bf16 bf16x8 __attribute__((ext_vector_type(8)));
typedef __bf16 bf16x4 __attribute__((ext_vector_type(4)));
typedef float  f32x4  __attribute__((ext_vector_type(4)));

#define MROWS 4096   // SEQ*BATCH
#define NQKV  6144   // 3*HIDDEN

__device__ __forceinline__ void g2l16(const void* g, void* l) {
  __builtin_amdgcn_global_load_lds(
      (const __attribute__((address_space(1))) unsigned int*)g,
      (__attribute__((address_space(3))) unsigned int*)l, 16, 0, 0);
}

// ---------------- fp32 -> bf16 convert ----------------
__global__ void cvt_kernel(const float* __restrict__ in, __bf16* __restrict__ out, int n4) {
  int i = blockIdx.x * 256 + threadIdx.x;
  if (i < n4) {
    float4 v = ((const float4*)in)[i];
    bf16x4 o = { (__bf16)v.x, (__bf16)v.y, (__bf16)v.z, (__bf16)v.w };
    ((bf16x4*)out)[i] = o;
  }
}

// ---------------- 2-phase GEMM: C[M][N] = A[M][K] * B[N][K]^T + bias --------
// 8 waves (2M x 4N): per-wave 16*MF rows x 16*NF cols. BM=32*MF, BN=64*NF.
// BK=64. Per K-tile: ph0 {read A-mh0 + all B; stage A1(kt+1)} MFMA(mh0);
// ph1 {read A-mh1; stage A0,B(kt+2)} MFMA(mh1); vmcnt(I_A+I_B); barrier.
// A regions: rows with (row/Q)%2==mh, Q=BM/4 (matches wm-half read split).
// Depth-2 pipeline over 2 buffers, 2-3 phase lead, vmcnt never 0 in loop.
// LDS swizzled chunk^=(row&7) via pre-swizzled global source (rule #21).
template<int MF, int NF, int C_BF16>
__global__ __launch_bounds__(512, 2)
void gemm8(const __bf16* __restrict__ A, const __bf16* __restrict__ B,
           const float* __restrict__ bias, void* __restrict__ Cout,
           int M, int N, int K) {
  constexpr int BM = 32 * MF, BN = 64 * NF;
  constexpr int Q = BM / 4;
  constexpr int ABYTES = BM * 128, BBYTES = BN * 128;
  constexpr int I_A = BM / 128;     // g2l16 per thread per A-region (8KB each)
  constexpr int I_B = BN / 64;      // g2l16 per thread for B tile

  const int tid = threadIdx.x, lane = tid & 63, w = tid >> 6;
  const int wm = w >> 2, wn = w & 3;
  const int m0 = blockIdx.y * BM, n0 = blockIdx.x * BN;
  const int fr = lane & 15, g = lane >> 4;
  const int r_off = lane >> 3;                  // row within 8-row unit
  const int swch = (lane & 7) ^ r_off;          // pre-swizzled global chunk

  __shared__ char smem[2][ABYTES + BBYTES];

  f32x4 acc[MF][NF] = {};
  bf16x8 afr[MF / 2][2], bfr[NF][2];

  const int nt = K >> 6;

  auto stageA = [&](int kt2, int mh) {
    char* base = smem[kt2 & 1];
    #pragma unroll
    for (int q = 0; q < I_A; ++q) {
      int uu = q * 8 + w;
      int s = uu / (Q / 8);
      int rb = (2 * s + mh) * Q + (uu % (Q / 8)) * 8;
      g2l16(A + (size_t)(m0 + rb + r_off) * K + kt2 * 64 + swch * 8,
            base + rb * 128);
    }
  };
  auto stageB = [&](int kt2) {
    char* base = smem[kt2 & 1] + ABYTES;
    #pragma unroll
    for (int q = 0; q < I_B; ++q) {
      int rb = (q * 8 + w) * 8;
      g2l16(B + (size_t)(n0 + rb + r_off) * K + kt2 * 64 + swch * 8,
            base + rb * 128);
    }
  };
  auto loadA = [&](int kt, int mh) {
    const char* ah = smem[kt & 1] + wm * (BM / 2) * 128;
    #pragma unroll
    for (int mf = 0; mf < MF / 2; ++mf) {
      int row = (mh * (MF / 2) + mf) * 16 + fr;
      #pragma unroll
      for (int ks = 0; ks < 2; ++ks)
        afr[mf][ks] = *(const bf16x8*)(ah + row * 128 + (((ks * 4 + g) ^ (row & 7)) << 4));
    }
  };
  auto loadB = [&](int kt) {
    const char* bh = smem[kt & 1] + ABYTES;
    #pragma unroll
    for (int nf = 0; nf < NF; ++nf) {
      int row = wn * (BN / 4) + nf * 16 + fr;
      #pragma unroll
      for (int ks = 0; ks < 2; ++ks)
        bfr[nf][ks] = *(const bf16x8*)(bh + row * 128 + (((ks * 4 + g) ^ (row & 7)) << 4));
    }
  };
  auto mfma_half = [&](int mh) {
    #pragma unroll
    for (int mf = 0; mf < MF / 2; ++mf)
      #pragma unroll
      for (int nf = 0; nf < NF; ++nf) {
        f32x4& a0 = acc[mh * (MF / 2) + mf][nf];
        a0 = __builtin_amdgcn_mfma_f32_16x16x32_bf16(afr[mf][0], bfr[nf][0], a0, 0, 0, 0);
        a0 = __builtin_amdgcn_mfma_f32_16x16x32_bf16(afr[mf][1], bfr[nf][1], a0, 0, 0, 0);
      }
  };

  // prologue: tile0 fully, tile1 A0+B (A1(1) comes at ph0(0))
  stageA(0, 0); stageB(0); stageA(0, 1);
  stageA(1, 0); stageB(1);
  asm volatile("s_waitcnt vmcnt(%0)" :: "i"(I_A + I_B) : "memory");
  asm volatile("s_barrier" ::: "memory");

  for (int kt = 0; kt < nt; ++kt) {
    // ph0: read A-mh0 + all B (buf[kt&1]); stage A1(kt+1) -> buf[(kt+1)&1]
    // (its region last read at ph1(kt-1), barrier-separated)
    loadA(kt, 0); loadB(kt);
    stageA(kt + 1, 1);
    asm volatile("s_barrier" ::: "memory");
    __builtin_amdgcn_s_setprio(1);
    mfma_half(0);
    __builtin_amdgcn_s_setprio(0);
    asm volatile("s_barrier" ::: "memory");
    // ph1: read A-mh1; stage A0,B(kt+2) -> buf[kt&1] (regions last read ph0,
    // all waves' reads consumed by mfma_half(0) before the barrier)
    loadA(kt, 1);
    stageA(kt + 2, 0); stageB(kt + 2);
    asm volatile("s_barrier" ::: "memory");
    __builtin_amdgcn_s_setprio(1);
    mfma_half(1);
    __builtin_amdgcn_s_setprio(0);
    // tile kt+1 fully landed (A1(kt+1) + older); kt+2's I_A+I_B may fly on
    asm volatile("s_waitcnt vmcnt(%0)" :: "i"(I_A + I_B) : "memory");
    asm volatile("s_barrier" ::: "memory");
  }
  // phantom stages (kt2 up to nt+1) read <=4.4KB past panel ends: all land in
  // adjacent mapped ws buffers and write LDS regions never read again.

  // epilogue: C/D layout col=lane&15, row=(lane>>4)*4+reg (m89/m91-verified)
  const int orow0 = m0 + wm * (BM / 2) + g * 4;
  const int ocol0 = n0 + wn * (BN / 4) + fr;
  #pragma unroll
  for (int nf = 0; nf < NF; ++nf) {
    int col = ocol0 + nf * 16;
    float bv = bias[col];
    #pragma unroll
    for (int mf = 0; mf < MF; ++mf) {
      #pragma unroll
      for (int r = 0; r < 4; ++r) {
        float v = acc[mf][nf][r] + bv;
        size_t idx = (size_t)(orow0 + mf * 16 + r) * N + col;
        if (C_BF16) ((__bf16*)Cout)[idx] = (__bf16)v;
        else        ((float*)Cout)[idx]  = v;
      }
    }
  }
}

// ---------------- V transpose: mixed V-slice -> vbuf[bn][d][t] ----------------
__global__ __launch_bounds__(256, 2)
void vtrans(const __bf16* __restrict__ mixed, __bf16* __restrict__ vbuf) {
  const int tid = threadIdx.x;
  const int bn = blockIdx.x;          // b*16 + n
  const int b = bn >> 4, n = bn & 15;
  const int t0 = blockIdx.y * 128;
  __shared__ __bf16 tile[128][128];   // swizzled: chunk ^= (row>>3)&7

  #pragma unroll
  for (int q = 0; q < 8; ++q) {
    int lin = q * 256 + tid;
    int r = lin >> 4, ch = lin & 15;
    bf16x8 v = *(const bf16x8*)(mixed + (size_t)(t0 + r) * 12288 + (size_t)b * 6144 + n * 384 + 256 + ch * 8);
    int sch = ch ^ ((r >> 3) & 7);
    *(bf16x8*)((char*)tile + r * 256 + sch * 16) = v;
  }
  __syncthreads();
  #pragma unroll
  for (int q = 0; q < 8; ++q) {
    int lin = q * 256 + tid;
    int d = lin >> 4, tc = (lin & 15) * 8;
    bf16x8 v;
    #pragma unroll
    for (int j = 0; j < 8; ++j) {
      int row = tc + j;
      int swb = (d * 2) ^ (((row >> 3) & 7) << 4);
      v[j] = *(const __bf16*)((const char*)tile + row * 256 + swb);
    }
    *(bf16x8*)(vbuf + ((size_t)bn * 128 + d) * 2048 + t0 + tc) = v;
  }
}

// ---------------- flash attention ----------------
// grid (8 pairs, 32 bn); 512 threads = 8 waves x 16 q-rows. Each block
// processes mirrored q-tiles (15-x) then (x): exactly 34 KV iters per block.
// LDS 84KB pins 1 block/CU -> deterministic 1:1 block->CU balance.
struct SmemA {
  __bf16 k[2][64][128];   // 32KB  (aliased by Q staging area)
  __bf16 v[2][128][64];   // 32KB
  __bf16 p[8][16][64];    // 16KB per-wave private P
};
union SmemUA { __bf16 q[128][128]; SmemA s; char pad[86016]; };

__global__ __launch_bounds__(512, 1)
void attn_kernel(const __bf16* __restrict__ mixed, const __bf16* __restrict__ vbuf,
                 __bf16* __restrict__ ctx) {
  const int tid = threadIdx.x, lane = tid & 63, w = tid >> 6;   // w in 0..7
  const int bn = blockIdx.y;
  const int b = bn >> 4, n = bn & 15;
  const int fr = lane & 15, g = lane >> 4;

  __shared__ SmemUA sm;
  const __bf16* vb = vbuf + (size_t)bn * 128 * 2048;
  const __bf16* mixb = mixed + (size_t)b * 6144 + n * 384;
  char* pbase = (char*)sm.s.p + w * 2048;

  auto stage_kv = [&](int k0, int buf) {
    #pragma unroll
    for (int qq = 0; qq < 2; ++qq) {
      int t = qq * 512 + tid;
      int r = t >> 4, ch = (t & 15) ^ (r & 7);
      g2l16(mixb + (size_t)(k0 + r) * 12288 + 128 + ch * 8,
            (char*)sm.s.k[buf] + qq * 8192 + w * 1024);
    }
    #pragma unroll
    for (int qq = 0; qq < 2; ++qq) {
      int t = qq * 512 + tid;
      int d = t >> 3, i = (t & 7) ^ (d & 7);
      g2l16(vb + (size_t)d * 2048 + k0 + i * 8,
            (char*)sm.s.v[buf] + qq * 8192 + w * 1024);
    }
  };

  #pragma unroll 1
  for (int phase = 0; phase < 2; ++phase) {
    const int qt = phase ? (int)blockIdx.x : (15 - (int)blockIdx.x);  // heavy first
    const int qs = qt * 128;

    __syncthreads();   // prior phase fully done before Q restage (aliases K dbuf)

    // ---- stage Q [128][128] (pre-swizzled source) ----
    #pragma unroll
    for (int qq = 0; qq < 4; ++qq) {
      int t = qq * 512 + tid;
      int r = t >> 4, ch = (t & 15) ^ (r & 7);
      g2l16(mixb + (size_t)(qs + r) * 12288 + ch * 8,
            (char*)sm.q + qq * 8192 + w * 1024);
    }
    asm volatile("s_waitcnt vmcnt(0)" ::: "memory");
    __syncthreads();

    bf16x8 qf[4];
    {
      const int row = w * 16 + fr;
      #pragma unroll
      for (int ks = 0; ks < 4; ++ks) {
        int ch = (ks * 4 + g) ^ (row & 7);
        qf[ks] = *(const bf16x8*)((const char*)sm.q + row * 256 + ch * 16);
      }
    }
    asm volatile("s_waitcnt lgkmcnt(0)" ::: "memory");
    __syncthreads();   // all qf reads landed before K staging overwrites Q area

    f32x4 O[8] = {};
    float mrun[4], lrun[4];
    #pragma unroll
    for (int j = 0; j < 4; ++j) { mrun[j] = -1e30f; lrun[j] = 0.f; }

    const int nt = (qs + 128) >> 6;
    int cur = 0;
    stage_kv(0, 0);

    #pragma unroll 1
    for (int it = 0; it < nt; ++it) {
      const int k0 = it * 64;
      asm volatile("s_waitcnt vmcnt(0)" ::: "memory");   // buf[cur] landed
      __syncthreads();                                    // ...for ALL waves
      if (it + 1 < nt) stage_kv((it + 1) * 64, cur ^ 1);  // fly under compute

      // ---- QK^T: S[16 q][64 kv] per wave ----
      f32x4 S[4] = {};
      __builtin_amdgcn_s_setprio(1);
      #pragma unroll
      for (int ks = 0; ks < 4; ++ks) {
        bf16x8 kf[4];
        #pragma unroll
        for (int fn = 0; fn < 4; ++fn) {
          int row = fn * 16 + fr;
          int ch = (ks * 4 + g) ^ (row & 7);
          kf[fn] = *(const bf16x8*)((const char*)sm.s.k[cur] + row * 256 + ch * 16);
        }
        #pragma unroll
        for (int fn = 0; fn < 4; ++fn)
          S[fn] = __builtin_amdgcn_mfma_f32_16x16x32_bf16(qf[ks], kf[fn], S[fn], 0, 0, 0);
      }
      __builtin_amdgcn_s_setprio(0);

      // scale + causal mask
      const float sc = 0.08838834764831845f;   // 1/sqrt(128)
      const bool needmask = (k0 + 63 > qs + w * 16);
      #pragma unroll
      for (int fn = 0; fn < 4; ++fn)
        #pragma unroll
        for (int r = 0; r < 4; ++r) {
          float v = S[fn][r] * sc;
          if (needmask) {
            int qrow = qs + w * 16 + g * 4 + r;
            int kcol = k0 + fn * 16 + fr;
            if (kcol > qrow) v = -1e30f;
          }
          S[fn][r] = v;
        }

      // ---- online softmax (16-lane shfl_xor reductions) ----
      #pragma unroll
      for (int r = 0; r < 4; ++r) {
        float mx = fmaxf(fmaxf(S[0][r], S[1][r]), fmaxf(S[2][r], S[3][r]));
        #pragma unroll
        for (int off = 1; off < 16; off <<= 1)
          mx = fmaxf(mx, __shfl_xor(mx, off));
        float mnew = fmaxf(mrun[r], mx);
        float scal = __expf(mrun[r] - mnew);
        mrun[r] = mnew;
        float rs = 0.f;
        #pragma unroll
        for (int fn = 0; fn < 4; ++fn) {
          float p = __expf(S[fn][r] - mnew);
          S[fn][r] = p;
          rs += p;
        }
        #pragma unroll
        for (int off = 1; off < 16; off <<= 1)
          rs += __shfl_xor(rs, off);
        lrun[r] = lrun[r] * scal + rs;
        #pragma unroll
        for (int fn2 = 0; fn2 < 8; ++fn2)
          O[fn2][r] *= scal;
      }

      // ---- P -> LDS (per-wave private, swizzled) ----
      #pragma unroll
      for (int fn = 0; fn < 4; ++fn)
        #pragma unroll
        for (int r = 0; r < 4; ++r) {
          int prow = g * 4 + r;
          int colb = (fn * 16 + fr) * 2;
          *(__bf16*)(pbase + prow * 128 + (colb ^ ((prow & 7) << 4))) = (__bf16)S[fn][r];
        }

      // ---- PV: O += P * V ----
      __builtin_amdgcn_s_setprio(1);
      #pragma unroll
      for (int ks2 = 0; ks2 < 2; ++ks2) {
        bf16x8 pa;
        {
          int ch = (ks2 * 4 + g) ^ (fr & 7);
          pa = *(const bf16x8*)(pbase + fr * 128 + ch * 16);
        }
        #pragma unroll
        for (int fn2 = 0; fn2 < 8; ++fn2) {
          int vrow = fn2 * 16 + fr;
          int ch = (ks2 * 4 + g) ^ (vrow & 7);
          bf16x8 vf = *(const bf16x8*)((const char*)sm.s.v[cur] + vrow * 128 + ch * 16);
          O[fn2] = __builtin_amdgcn_mfma_f32_16x16x32_bf16(pa, vf, O[fn2], 0, 0, 0);
        }
      }
      __builtin_amdgcn_s_setprio(0);
      cur ^= 1;
    }

    // ---- epilogue: ctx[m][h] bf16 ----
    #pragma unroll
    for (int r = 0; r < 4; ++r) {
      int qrow = qs + w * 16 + g * 4 + r;
      float inv = 1.f / lrun[r];
      size_t rowb = ((size_t)qrow * 2 + b) * 2048 + n * 128;
      #pragma unroll
      for (int fn2 = 0; fn2 < 8; ++fn2)
        ctx[rowb + fn2 * 16 + fr] = (__bf16)(O[fn2][r] * inv);
    }
  }
}

extern "C" void kernel_launch(void* const* d_in, const int* in_sizes, int n_in,
                              void* d_out, int out_size, void* d_ws, size_t ws_size,
                              hipStream_t stream) {
  const float* x    = (const float*)d_in[0];
  // d_in[1] = mask: structurally causal, applied analytically in attn_kernel
  const float* wqkv = (const float*)d_in[2];
  const float* bqkv = (const float*)d_in[3];
  const float* wd   = (const float*)d_in[4];
  const float* bd   = (const float*)d_in[5];

  char* ws = (char*)d_ws;
  __bf16* xb    = (__bf16*)(ws);                 // 16.8MB (reused as ctx later)
  __bf16* wqkvb = (__bf16*)(ws + 16777216);      // 25.2MB
  __bf16* wdb   = (__bf16*)(ws + 41943040);      // 8.4MB
  __bf16* mixed = (__bf16*)(ws + 50331648);      // 50.3MB
  __bf16* vbuf  = (__bf16*)(ws + 100663296);     // 16.8MB  (total 117.4MB)
  __bf16* ctx   = xb;                            // xb dead after QKV GEMM

  cvt_kernel<<<dim3(8192),  256, 0, stream>>>(x,    xb,    2097152);
  cvt_kernel<<<dim3(12288), 256, 0, stream>>>(wqkv, wqkvb, 3145728);
  cvt_kernel<<<dim3(4096),  256, 0, stream>>>(wd,   wdb,   1048576);

  // QKV: BM=256 x BN=192 -> grid 32x16 = 512 blocks = 2 exact rounds @1/CU
  gemm8<8,3,1><<<dim3(32, 16), 512, 0, stream>>>(xb, wqkvb, bqkv, (void*)mixed, MROWS, NQKV, 2048);
  vtrans<<<dim3(32, 16), 256, 0, stream>>>(mixed, vbuf);
  attn_kernel<<<dim3(8, 32), 512, 0, stream>>>(mixed, vbuf, ctx);
  // dense: BM=128 x BN=256 -> grid 8x32 = 256 blocks = 1 exact round
  gemm8<4,4,0><<<dim3(8, 32), 512, 0, stream>>>(ctx, wdb, bd, d_out, MROWS, 2048, 2048);
}

// Round 5
// 250.000 us; speedup vs baseline: 1.4721x; 1.0636x over previous
//
#include <hip/hip_runtime.h>
#include <hip/hip_bf16.h>

// Fused attention block: QKV proj -> causal MHA -> dense proj.
// SEQ=2048, BATCH=2, HIDDEN=2048, HEADS=16, HEAD_DIM=128.
// R5: GEMMs on the faithful m201 4-phase/K-tile schedule: per phase
// {ds-read subtile + ONE half-tile stage; barrier; lgkmcnt(0); setprio;
// MFMA cluster; setprio; barrier}, Gray-coded C-quadrants, one counted
// vmcnt per K-tile (never 0). QKV 256x192 grid 512 (2 exact rounds),
// dense 128x256 grid 256 (1 round). cvt merged into one launch.

typedef __bf16 bf16x8 __attribute__((ext_vector_type(8)));
typedef __bf16 bf16x4 __attribute__((ext_vector_type(4)));
typedef float  f32x4  __attribute__((ext_vector_type(4)));

#define MROWS 4096   // SEQ*BATCH
#define NQKV  6144   // 3*HIDDEN

__device__ __forceinline__ void g2l16(const void* g, void* l) {
  __builtin_amdgcn_global_load_lds(
      (const __attribute__((address_space(1))) unsigned int*)g,
      (__attribute__((address_space(3))) unsigned int*)l, 16, 0, 0);
}

// ---------------- fp32 -> bf16 convert (all three tensors, one launch) ------
__global__ void cvt3_kernel(const float* __restrict__ x, const float* __restrict__ wq,
                            const float* __restrict__ wd, __bf16* __restrict__ xb,
                            __bf16* __restrict__ wqb, __bf16* __restrict__ wdb) {
  const int N1 = 2097152, N2 = 3145728;   // float4 counts: x, wqkv (wd = rest)
  int i = blockIdx.x * 256 + threadIdx.x;
  const float4* src; bf16x4* dst; int j;
  if (i < N1)           { src = (const float4*)x;  dst = (bf16x4*)xb;  j = i; }
  else if (i < N1 + N2) { src = (const float4*)wq; dst = (bf16x4*)wqb; j = i - N1; }
  else                  { src = (const float4*)wd; dst = (bf16x4*)wdb; j = i - N1 - N2; }
  float4 v = src[j];
  bf16x4 o = { (__bf16)v.x, (__bf16)v.y, (__bf16)v.z, (__bf16)v.w };
  dst[j] = o;
}

// ---------------- 4-phase GEMM: C[M][N] = A[M][K] * B[N][K]^T + bias --------
// 8 waves (2M x 4N). BM=32*MF, BN=64*NF, BK=64. Per-wave 16*MF x 16*NF.
// A regions: mh-halves (rows (mh*MF/2+mf)*16 within each wm-half).
// B regions: G0 = frags {0,1} (128 rows), G1 = frags {2..NF-1}.
// Phases (Gray order on C-quadrants): ph0 (mh0,G0), ph1 (mh0,G1),
// ph2 (mh1,G1), ph3 (mh1,G0 - regs held, no reads).
// Stages: ph0->A1(kt+1), ph1->BG1(kt+1) [other buffer]; ph2->A0(kt+2),
// ph3->BG0(kt+2) [current buffer, after that region's last read].
// Boundary vmcnt(LA+2) drains tile kt+1 exactly; kt+2 stages stay in flight.
// LDS swizzle chunk^=(row&7) via pre-swizzled global source (rule #21).
#define MM_CL(MH, NFI)                                                          \
  { _Pragma("unroll")                                                           \
    for (int mf = 0; mf < MF/2; ++mf) {                                         \
      f32x4& a0 = acc[(MH)*(MF/2)+mf][NFI];                                     \
      a0 = __builtin_amdgcn_mfma_f32_16x16x32_bf16(afr[mf][0], bfr[NFI][0], a0, 0,0,0); \
      a0 = __builtin_amdgcn_mfma_f32_16x16x32_bf16(afr[mf][1], bfr[NFI][1], a0, 0,0,0); \
    } }
#define LDB(NFI)                                                                \
  { int row = wn*(BN/4) + (NFI)*16 + fr;                                        \
    _Pragma("unroll")                                                           \
    for (int ks = 0; ks < 2; ++ks)                                              \
      bfr[NFI][ks] = *(const bf16x8*)(buf + ABYTES + row*128 + (((ks*4+g)^(row&7))<<4)); }
#define SBAR asm volatile("s_barrier" ::: "memory")
#define LGKM0 asm volatile("s_waitcnt lgkmcnt(0)" ::: "memory")

template<int MF, int NF, int C_BF16>
__global__ __launch_bounds__(512, 1)
void gemm4p(const __bf16* __restrict__ A, const __bf16* __restrict__ B,
            const float* __restrict__ bias, void* __restrict__ Cout,
            int M, int N, int K) {
  constexpr int BM = 32*MF, BN = 64*NF;
  constexpr int ABYTES = BM*128;
  constexpr int LA = BM/128;        // g2l16/thread per A-region
  constexpr int LG1 = NF-2;         // g2l16/thread for B-G1
  constexpr int VMC = LA + 2;       // boundary vmcnt

  const int tid = threadIdx.x, lane = tid & 63, w = tid >> 6;
  const int wm = w >> 2, wn = w & 3;
  const int m0 = blockIdx.y*BM, n0 = blockIdx.x*BN;
  const int fr = lane & 15, g = lane >> 4;
  const int l8 = lane >> 3;
  const int swch = (lane & 7) ^ l8;

  __shared__ char smem[2][ABYTES + BN*128];

  f32x4 acc[MF][NF] = {};
  bf16x8 afr[MF/2][2], bfr[NF][2];

  const int nt = K >> 6;

  auto stA = [&](int kt2, int mh, char* dst) {
    #pragma unroll
    for (int q = 0; q < LA; ++q) {
      int idx0 = q*64 + w*8;                     // wave-uniform unit start
      int h = idx0 / (BM/4), ris = idx0 % (BM/4);
      int drow = h*(BM/2) + mh*(BM/4) + ris;
      g2l16(A + (size_t)(m0 + drow + l8)*K + kt2*64 + swch*8, dst + drow*128);
    }
  };
  auto stB0 = [&](int kt2, char* dst) {          // G0: 4 strips of 32 rows
    #pragma unroll
    for (int q = 0; q < 2; ++q) {
      int idx0 = q*64 + w*8;
      int drow = (idx0 >> 5)*(BN/4) + (idx0 & 31);
      g2l16(B + (size_t)(n0 + drow + l8)*K + kt2*64 + swch*8, dst + ABYTES + drow*128);
    }
  };
  auto stB1 = [&](int kt2, char* dst) {          // G1: 4 strips of (NF-2)*16
    #pragma unroll
    for (int q = 0; q < LG1; ++q) {
      int idx0 = q*64 + w*8;
      int drow = (idx0 / ((NF-2)*16))*(BN/4) + 32 + idx0 % ((NF-2)*16);
      g2l16(B + (size_t)(n0 + drow + l8)*K + kt2*64 + swch*8, dst + ABYTES + drow*128);
    }
  };
  auto ldA = [&](const char* buf, int mh) {
    const char* ah = buf + wm*(BM/2)*128;
    #pragma unroll
    for (int mf = 0; mf < MF/2; ++mf) {
      int row = (mh*(MF/2)+mf)*16 + fr;
      #pragma unroll
      for (int ks = 0; ks < 2; ++ks)
        afr[mf][ks] = *(const bf16x8*)(ah + row*128 + (((ks*4+g)^(row&7))<<4));
    }
  };

  auto tile = [&](int kt, char* buf, char* nbuf) {
    // ph0: read A-mh0 + B-G0; stage A1(kt+1)->nbuf
    ldA(buf, 0); LDB(0); LDB(1);
    stA(kt+1, 1, nbuf);
    if constexpr (NF == 3) { asm volatile("s_waitcnt lgkmcnt(8)" ::: "memory"); }
    SBAR; LGKM0;
    __builtin_amdgcn_s_setprio(1); MM_CL(0,0); MM_CL(0,1); __builtin_amdgcn_s_setprio(0);
    SBAR;
    // ph1: read B-G1; stage B-G1(kt+1)->nbuf
    LDB(2); if constexpr (NF == 4) { LDB(3); }
    stB1(kt+1, nbuf);
    SBAR; LGKM0;
    __builtin_amdgcn_s_setprio(1); MM_CL(0,2); if constexpr (NF == 4) { MM_CL(0,3); } __builtin_amdgcn_s_setprio(0);
    SBAR;
    // ph2: read A-mh1; stage A0(kt+2)->buf (A0 reads done at ph0)
    ldA(buf, 1);
    stA(kt+2, 0, buf);
    SBAR; LGKM0;
    __builtin_amdgcn_s_setprio(1); MM_CL(1,2); if constexpr (NF == 4) { MM_CL(1,3); } __builtin_amdgcn_s_setprio(0);
    SBAR;
    // ph3: no reads (B-G0 frags held); stage B-G0(kt+2)->buf (reads done ph0);
    // then counted drain: tile kt+1 fully landed, kt+2 stages stay in flight.
    stB0(kt+2, buf);
    SBAR;
    __builtin_amdgcn_s_setprio(1); MM_CL(1,0); MM_CL(1,1); __builtin_amdgcn_s_setprio(0);
    asm volatile("s_waitcnt vmcnt(%0)" :: "i"(VMC) : "memory");
    SBAR;
  };

  // prologue: tile0 complete + A0,BG0 of tile1; newest LA+2 loads may fly
  stA(0, 0, smem[0]); stB0(0, smem[0]); stB1(0, smem[0]); stA(0, 1, smem[0]);
  stA(1, 0, smem[1]); stB0(1, smem[1]);
  asm volatile("s_waitcnt vmcnt(%0)" :: "i"(VMC) : "memory");
  SBAR;

  for (int kt = 0; kt < nt; kt += 2) {
    tile(kt,     smem[0], smem[1]);
    tile(kt + 1, smem[1], smem[0]);
  }
  // phantom stages (kt2 up to nt+1) read <=256B past panel ends into adjacent
  // mapped ws buffers; their LDS regions are never read again.

  // epilogue: C/D layout col=lane&15, row=(lane>>4)*4+reg (m89/m91-verified)
  const int orow0 = m0 + wm*(BM/2) + g*4;
  const int ocol0 = n0 + wn*(BN/4) + fr;
  #pragma unroll
  for (int nf = 0; nf < NF; ++nf) {
    int col = ocol0 + nf*16;
    float bv = bias[col];
    #pragma unroll
    for (int mf = 0; mf < MF; ++mf) {
      #pragma unroll
      for (int r = 0; r < 4; ++r) {
        float v = acc[mf][nf][r] + bv;
        size_t idx = (size_t)(orow0 + mf*16 + r) * N + col;
        if (C_BF16) ((__bf16*)Cout)[idx] = (__bf16)v;
        else        ((float*)Cout)[idx]  = v;
      }
    }
  }
}

// ---------------- V transpose: mixed V-slice -> vbuf[bn][d][t] ----------------
__global__ __launch_bounds__(256, 2)
void vtrans(const __bf16* __restrict__ mixed, __bf16* __restrict__ vbuf) {
  const int tid = threadIdx.x;
  const int bn = blockIdx.x;          // b*16 + n
  const int b = bn >> 4, n = bn & 15;
  const int t0 = blockIdx.y * 128;
  __shared__ __bf16 tile[128][128];   // swizzled: chunk ^= (row>>3)&7

  #pragma unroll
  for (int q = 0; q < 8; ++q) {
    int lin = q * 256 + tid;
    int r = lin >> 4, ch = lin & 15;
    bf16x8 v = *(const bf16x8*)(mixed + (size_t)(t0 + r) * 12288 + (size_t)b * 6144 + n * 384 + 256 + ch * 8);
    int sch = ch ^ ((r >> 3) & 7);
    *(bf16x8*)((char*)tile + r * 256 + sch * 16) = v;
  }
  __syncthreads();
  #pragma unroll
  for (int q = 0; q < 8; ++q) {
    int lin = q * 256 + tid;
    int d = lin >> 4, tc = (lin & 15) * 8;
    bf16x8 v;
    #pragma unroll
    for (int j = 0; j < 8; ++j) {
      int row = tc + j;
      int swb = (d * 2) ^ (((row >> 3) & 7) << 4);
      v[j] = *(const __bf16*)((const char*)tile + row * 256 + swb);
    }
    *(bf16x8*)(vbuf + ((size_t)bn * 128 + d) * 2048 + t0 + tc) = v;
  }
}

// ---------------- flash attention ----------------
// grid (8 pairs, 32 bn); 512 threads = 8 waves x 16 q-rows. Each block
// processes mirrored q-tiles (15-x) then (x): exactly 34 KV iters per block.
// LDS 84KB pins 1 block/CU -> deterministic 1:1 block->CU balance.
struct SmemA {
  __bf16 k[2][64][128];   // 32KB  (aliased by Q staging area)
  __bf16 v[2][128][64];   // 32KB
  __bf16 p[8][16][64];    // 16KB per-wave private P
};
union SmemUA { __bf16 q[128][128]; SmemA s; char pad[86016]; };

__global__ __launch_bounds__(512, 1)
void attn_kernel(const __bf16* __restrict__ mixed, const __bf16* __restrict__ vbuf,
                 __bf16* __restrict__ ctx) {
  const int tid = threadIdx.x, lane = tid & 63, w = tid >> 6;   // w in 0..7
  const int bn = blockIdx.y;
  const int b = bn >> 4, n = bn & 15;
  const int fr = lane & 15, g = lane >> 4;

  __shared__ SmemUA sm;
  const __bf16* vb = vbuf + (size_t)bn * 128 * 2048;
  const __bf16* mixb = mixed + (size_t)b * 6144 + n * 384;
  char* pbase = (char*)sm.s.p + w * 2048;

  auto stage_kv = [&](int k0, int buf) {
    #pragma unroll
    for (int qq = 0; qq < 2; ++qq) {
      int t = qq * 512 + tid;
      int r = t >> 4, ch = (t & 15) ^ (r & 7);
      g2l16(mixb + (size_t)(k0 + r) * 12288 + 128 + ch * 8,
            (char*)sm.s.k[buf] + qq * 8192 + w * 1024);
    }
    #pragma unroll
    for (int qq = 0; qq < 2; ++qq) {
      int t = qq * 512 + tid;
      int d = t >> 3, i = (t & 7) ^ (d & 7);
      g2l16(vb + (size_t)d * 2048 + k0 + i * 8,
            (char*)sm.s.v[buf] + qq * 8192 + w * 1024);
    }
  };

  #pragma unroll 1
  for (int phase = 0; phase < 2; ++phase) {
    const int qt = phase ? (int)blockIdx.x : (15 - (int)blockIdx.x);  // heavy first
    const int qs = qt * 128;

    __syncthreads();   // prior phase fully done before Q restage (aliases K dbuf)

    // ---- stage Q [128][128] (pre-swizzled source) ----
    #pragma unroll
    for (int qq = 0; qq < 4; ++qq) {
      int t = qq * 512 + tid;
      int r = t >> 4, ch = (t & 15) ^ (r & 7);
      g2l16(mixb + (size_t)(qs + r) * 12288 + ch * 8,
            (char*)sm.q + qq * 8192 + w * 1024);
    }
    asm volatile("s_waitcnt vmcnt(0)" ::: "memory");
    __syncthreads();

    bf16x8 qf[4];
    {
      const int row = w * 16 + fr;
      #pragma unroll
      for (int ks = 0; ks < 4; ++ks) {
        int ch = (ks * 4 + g) ^ (row & 7);
        qf[ks] = *(const bf16x8*)((const char*)sm.q + row * 256 + ch * 16);
      }
    }
    asm volatile("s_waitcnt lgkmcnt(0)" ::: "memory");
    __syncthreads();   // all qf reads landed before K staging overwrites Q area

    f32x4 O[8] = {};
    float mrun[4], lrun[4];
    #pragma unroll
    for (int j = 0; j < 4; ++j) { mrun[j] = -1e30f; lrun[j] = 0.f; }

    const int nt = (qs + 128) >> 6;
    int cur = 0;
    stage_kv(0, 0);

    #pragma unroll 1
    for (int it = 0; it < nt; ++it) {
      const int k0 = it * 64;
      asm volatile("s_waitcnt vmcnt(0)" ::: "memory");   // buf[cur] landed
      __syncthreads();                                    // ...for ALL waves
      if (it + 1 < nt) stage_kv((it + 1) * 64, cur ^ 1);  // fly under compute

      // ---- QK^T: S[16 q][64 kv] per wave ----
      f32x4 S[4] = {};
      __builtin_amdgcn_s_setprio(1);
      #pragma unroll
      for (int ks = 0; ks < 4; ++ks) {
        bf16x8 kf[4];
        #pragma unroll
        for (int fn = 0; fn < 4; ++fn) {
          int row = fn * 16 + fr;
          int ch = (ks * 4 + g) ^ (row & 7);
          kf[fn] = *(const bf16x8*)((const char*)sm.s.k[cur] + row * 256 + ch * 16);
        }
        #pragma unroll
        for (int fn = 0; fn < 4; ++fn)
          S[fn] = __builtin_amdgcn_mfma_f32_16x16x32_bf16(qf[ks], kf[fn], S[fn], 0, 0, 0);
      }
      __builtin_amdgcn_s_setprio(0);

      // scale + causal mask
      const float sc = 0.08838834764831845f;   // 1/sqrt(128)
      const bool needmask = (k0 + 63 > qs + w * 16);
      #pragma unroll
      for (int fn = 0; fn < 4; ++fn)
        #pragma unroll
        for (int r = 0; r < 4; ++r) {
          float v = S[fn][r] * sc;
          if (needmask) {
            int qrow = qs + w * 16 + g * 4 + r;
            int kcol = k0 + fn * 16 + fr;
            if (kcol > qrow) v = -1e30f;
          }
          S[fn][r] = v;
        }

      // ---- online softmax (16-lane shfl_xor reductions) ----
      #pragma unroll
      for (int r = 0; r < 4; ++r) {
        float mx = fmaxf(fmaxf(S[0][r], S[1][r]), fmaxf(S[2][r], S[3][r]));
        #pragma unroll
        for (int off = 1; off < 16; off <<= 1)
          mx = fmaxf(mx, __shfl_xor(mx, off));
        float mnew = fmaxf(mrun[r], mx);
        float scal = __expf(mrun[r] - mnew);
        mrun[r] = mnew;
        float rs = 0.f;
        #pragma unroll
        for (int fn = 0; fn < 4; ++fn) {
          float p = __expf(S[fn][r] - mnew);
          S[fn][r] = p;
          rs += p;
        }
        #pragma unroll
        for (int off = 1; off < 16; off <<= 1)
          rs += __shfl_xor(rs, off);
        lrun[r] = lrun[r] * scal + rs;
        #pragma unroll
        for (int fn2 = 0; fn2 < 8; ++fn2)
          O[fn2][r] *= scal;
      }

      // ---- P -> LDS (per-wave private, swizzled) ----
      #pragma unroll
      for (int fn = 0; fn < 4; ++fn)
        #pragma unroll
        for (int r = 0; r < 4; ++r) {
          int prow = g * 4 + r;
          int colb = (fn * 16 + fr) * 2;
          *(__bf16*)(pbase + prow * 128 + (colb ^ ((prow & 7) << 4))) = (__bf16)S[fn][r];
        }

      // ---- PV: O += P * V ----
      __builtin_amdgcn_s_setprio(1);
      #pragma unroll
      for (int ks2 = 0; ks2 < 2; ++ks2) {
        bf16x8 pa;
        {
          int ch = (ks2 * 4 + g) ^ (fr & 7);
          pa = *(const bf16x8*)(pbase + fr * 128 + ch * 16);
        }
        #pragma unroll
        for (int fn2 = 0; fn2 < 8; ++fn2) {
          int vrow = fn2 * 16 + fr;
          int ch = (ks2 * 4 + g) ^ (vrow & 7);
          bf16x8 vf = *(const bf16x8*)((const char*)sm.s.v[cur] + vrow * 128 + ch * 16);
          O[fn2] = __builtin_amdgcn_mfma_f32_16x16x32_bf16(pa, vf, O[fn2], 0, 0, 0);
        }
      }
      __builtin_amdgcn_s_setprio(0);
      cur ^= 1;
    }

    // ---- epilogue: ctx[m][h] bf16 ----
    #pragma unroll
    for (int r = 0; r < 4; ++r) {
      int qrow = qs + w * 16 + g * 4 + r;
      float inv = 1.f / lrun[r];
      size_t rowb = ((size_t)qrow * 2 + b) * 2048 + n * 128;
      #pragma unroll
      for (int fn2 = 0; fn2 < 8; ++fn2)
        ctx[rowb + fn2 * 16 + fr] = (__bf16)(O[fn2][r] * inv);
    }
  }
}

extern "C" void kernel_launch(void* const* d_in, const int* in_sizes, int n_in,
                              void* d_out, int out_size, void* d_ws, size_t ws_size,
                              hipStream_t stream) {
  const float* x    = (const float*)d_in[0];
  // d_in[1] = mask: structurally causal, applied analytically in attn_kernel
  const float* wqkv = (const float*)d_in[2];
  const float* bqkv = (const float*)d_in[3];
  const float* wd   = (const float*)d_in[4];
  const float* bd   = (const float*)d_in[5];

  char* ws = (char*)d_ws;
  __bf16* xb    = (__bf16*)(ws);                 // 16.8MB (reused as ctx later)
  __bf16* wqkvb = (__bf16*)(ws + 16777216);      // 25.2MB
  __bf16* wdb   = (__bf16*)(ws + 41943040);      // 8.4MB
  __bf16* mixed = (__bf16*)(ws + 50331648);      // 50.3MB
  __bf16* vbuf  = (__bf16*)(ws + 100663296);     // 16.8MB  (total 117.4MB)
  __bf16* ctx   = xb;                            // xb dead after QKV GEMM

  cvt3_kernel<<<dim3(24576), 256, 0, stream>>>(x, wqkv, wd, xb, wqkvb, wdb);

  // QKV: BM=256 x BN=192 -> grid 32x16 = 512 blocks = 2 exact rounds @1/CU
  gemm4p<8,3,1><<<dim3(32, 16), 512, 0, stream>>>(xb, wqkvb, bqkv, (void*)mixed, MROWS, NQKV, 2048);
  vtrans<<<dim3(32, 16), 256, 0, stream>>>(mixed, vbuf);
  attn_kernel<<<dim3(8, 32), 512, 0, stream>>>(mixed, vbuf, ctx);
  // dense: BM=128 x BN=256 -> grid 8x32 = 256 blocks = 1 exact round
  gemm4p<4,4,0><<<dim3(8, 32), 512, 0, stream>>>(ctx, wdb, bd, d_out, MROWS, 2048, 2048);
}